// Round 1
// baseline (39.223 us; speedup 1.0000x reference)
//
#include <hip/hip_runtime.h>

// LinearAccInterpolation: B x (NKP keyframes) x DIM=2, STEP=4 spacing.
// Per segment i (n = idx[i+1]-idx[i]):
//   da = (dy - n*v0 - n(n+1)/2*a0) / (n(n+1)(n+2)/6)
//   pos_k = y0 + k*v0 + k(k+1)/2*a0 + k(k+1)(k+2)/6*da   (k=1..n)
//   v0 += n*a0 + n(n+1)/2*da ;  a0 += n*da
// n<=1: emit y1; a0 = (y1-y0) - v0; v0 = y1-y0.
//
// Mapping: 4 lanes per batch element. Each lane redundantly runs the
// 10-step recurrence (cheap) and writes rows k = r+1, r+5, ... so each
// 4-lane group stores 32B contiguous per segment (write coalescing).

__global__ __launch_bounds__(256) void interp_kernel(
    const int* __restrict__ index,
    const float2* __restrict__ value,      // B x NKP
    const float2* __restrict__ vinit,      // B x 1
    const float2* __restrict__ ainit,      // B x 1
    float2* __restrict__ out,              // B x rows
    int B, int nkp, int rows)
{
    int gid = blockIdx.x * 256 + threadIdx.x;
    int b = gid >> 2;
    int r = gid & 3;
    if (b >= B) return;

    float2 v0 = vinit[b];
    float2 a0 = ainit[b];
    const float2* __restrict__ vrow = value + (long)b * nkp;
    float2* __restrict__ orow = out + (long)b * rows;

    float2 y0 = vrow[0];
    int x0 = index[0];
    int off = 0;
    int nseg = nkp - 1;

    for (int i = 0; i < nseg; ++i) {
        float2 y1 = vrow[i + 1];
        int x1 = index[i + 1];
        int n = x1 - x0;
        x0 = x1;
        float dyx = y1.x - y0.x;
        float dyy = y1.y - y0.y;

        if (n <= 1) {
            if (r == 0) orow[off] = y1;
            off += 1;
            a0.x = dyx - v0.x;
            a0.y = dyy - v0.y;
            v0.x = dyx;
            v0.y = dyy;
        } else {
            float fn = (float)n;
            float c1 = fn * (fn + 1.0f) * 0.5f;             // n(n+1)/2
            float c2 = fn * (fn + 1.0f) * (fn + 2.0f) / 6.0f; // n(n+1)(n+2)/6
            float dax = (dyx - fn * v0.x - c1 * a0.x) / c2;
            float day = (dyy - fn * v0.y - c1 * a0.y) / c2;

            // lane r writes rows k = r+1, r+5, ... (single iter when n==4)
            for (int k = r + 1; k <= n; k += 4) {
                float fk = (float)k;
                float t2 = fk * (fk + 1.0f) * 0.5f;
                float t3 = fk * (fk + 1.0f) * (fk + 2.0f) * (1.0f / 6.0f);
                float2 p;
                p.x = y0.x + fk * v0.x + t2 * a0.x + t3 * dax;
                p.y = y0.y + fk * v0.y + t2 * a0.y + t3 * day;
                orow[off + k - 1] = p;
            }
            off += n;

            v0.x += fn * a0.x + c1 * dax;
            v0.y += fn * a0.y + c1 * day;
            a0.x += fn * dax;
            a0.y += fn * day;
        }
        y0 = y1;
    }
}

extern "C" void kernel_launch(void* const* d_in, const int* in_sizes, int n_in,
                              void* d_out, int out_size, void* d_ws, size_t ws_size,
                              hipStream_t stream) {
    const int*    index = (const int*)d_in[0];
    const float2* value = (const float2*)d_in[1];
    const float2* vinit = (const float2*)d_in[2];
    const float2* ainit = (const float2*)d_in[3];
    float2*       out   = (float2*)d_out;

    int nkp  = in_sizes[0];                 // 11
    int B    = in_sizes[1] / (nkp * 2);     // 262144
    int rows = out_size / (B * 2);          // 40

    int total = B * 4;                      // 4 lanes per batch element
    dim3 grid((total + 255) / 256);
    interp_kernel<<<grid, 256, 0, stream>>>(index, value, vinit, ainit, out, B, nkp, rows);
}

// Round 2
// 29.901 us; speedup vs baseline: 1.3117x; 1.3117x over previous
//
#include <hip/hip_runtime.h>

// LinearAccInterpolation: B x (NKP keyframes) x DIM=2.
// Per segment i (n = idx[i+1]-idx[i]):
//   da = (dy - n*v0 - n(n+1)/2*a0) / (n(n+1)(n+2)/6)
//   pos_k = y0 + k*v0 + k(k+1)/2*a0 + k(k+1)(k+2)/6*da   (k=1..n)
//   v0 += n*a0 + n(n+1)/2*da ;  a0 += n*da
// n<=1: emit y1; a0 = (y1-y0) - v0; v0 = y1-y0.
//
// Mapping: 4 lanes per batch element run the 10-step recurrence
// redundantly (cheap); lane r writes rows k=r+1, r+5, ... into an LDS
// staging tile [64 batches][rows]. After a barrier the block copies the
// tile out as fully-coalesced float4 stores (1 KB contiguous per wave
// store, 64B-line aligned) — fixes the 1.6x HBM write amplification seen
// with direct 32B-granular stores.

__global__ __launch_bounds__(256) void interp_kernel(
    const int* __restrict__ index,
    const float2* __restrict__ value,      // B x NKP
    const float2* __restrict__ vinit,      // B x 1
    const float2* __restrict__ ainit,      // B x 1
    float2* __restrict__ out,              // B x rows
    int B, int nkp, int rows)
{
    extern __shared__ float2 lds[];        // [64][rows]

    int tid = threadIdx.x;
    int gid = blockIdx.x * 256 + tid;
    int b  = gid >> 2;                     // global batch
    int r  = gid & 3;                      // lane-in-group
    int bl = tid >> 2;                     // local batch 0..63

    if (b < B) {
        float2 v0 = vinit[b];
        float2 a0 = ainit[b];
        const float2* __restrict__ vrow = value + (long)b * nkp;
        float2* __restrict__ lrow = lds + bl * rows;

        float2 y0 = vrow[0];
        int x0 = index[0];
        int off = 0;
        int nseg = nkp - 1;

        for (int i = 0; i < nseg; ++i) {
            float2 y1 = vrow[i + 1];
            int x1 = index[i + 1];
            int n = x1 - x0;
            x0 = x1;
            float dyx = y1.x - y0.x;
            float dyy = y1.y - y0.y;

            if (n <= 1) {
                if (r == 0) lrow[off] = y1;
                off += 1;
                a0.x = dyx - v0.x;
                a0.y = dyy - v0.y;
                v0.x = dyx;
                v0.y = dyy;
            } else {
                float fn = (float)n;
                float c1 = fn * (fn + 1.0f) * 0.5f;               // n(n+1)/2
                float c2 = fn * (fn + 1.0f) * (fn + 2.0f) / 6.0f; // n(n+1)(n+2)/6
                float dax = (dyx - fn * v0.x - c1 * a0.x) / c2;
                float day = (dyy - fn * v0.y - c1 * a0.y) / c2;

                for (int k = r + 1; k <= n; k += 4) {
                    float fk = (float)k;
                    float t2 = fk * (fk + 1.0f) * 0.5f;
                    float t3 = fk * (fk + 1.0f) * (fk + 2.0f) * (1.0f / 6.0f);
                    float2 p;
                    p.x = y0.x + fk * v0.x + t2 * a0.x + t3 * dax;
                    p.y = y0.y + fk * v0.y + t2 * a0.y + t3 * day;
                    lrow[off + k - 1] = p;
                }
                off += n;

                v0.x += fn * a0.x + c1 * dax;
                v0.y += fn * a0.y + c1 * day;
                a0.x += fn * dax;
                a0.y += fn * day;
            }
            y0 = y1;
        }
    }

    __syncthreads();

    // Coalesced copy-out: this block covers batches [blockIdx*64, +nb)
    int first_b = blockIdx.x * 64;
    int nb = B - first_b;
    if (nb > 64) nb = 64;
    if (nb <= 0) return;

    long base2 = (long)first_b * rows;          // float2 offset into out
    int total2 = nb * rows;                     // float2 elements to write
    int total4 = total2 >> 1;                   // full float4s
    const float4* __restrict__ l4 = (const float4*)lds;
    float4* __restrict__ o4 = (float4*)(out + base2);
    for (int f = tid; f < total4; f += 256) {
        o4[f] = l4[f];
    }
    if ((total2 & 1) && tid == 0) {             // odd tail (not hit for rows=40)
        out[base2 + total2 - 1] = lds[total2 - 1];
    }
}

extern "C" void kernel_launch(void* const* d_in, const int* in_sizes, int n_in,
                              void* d_out, int out_size, void* d_ws, size_t ws_size,
                              hipStream_t stream) {
    const int*    index = (const int*)d_in[0];
    const float2* value = (const float2*)d_in[1];
    const float2* vinit = (const float2*)d_in[2];
    const float2* ainit = (const float2*)d_in[3];
    float2*       out   = (float2*)d_out;

    int nkp  = in_sizes[0];                 // 11
    int B    = in_sizes[1] / (nkp * 2);     // 262144
    int rows = out_size / (B * 2);          // 40

    int total = B * 4;                      // 4 lanes per batch element
    dim3 grid((total + 255) / 256);
    size_t smem = (size_t)64 * rows * sizeof(float2);  // 20 KB for rows=40
    interp_kernel<<<grid, 256, smem, stream>>>(index, value, vinit, ainit, out, B, nkp, rows);
}

// Round 3
// 28.093 us; speedup vs baseline: 1.3962x; 1.0644x over previous
//
#include <hip/hip_runtime.h>

// LinearAccInterpolation: B x (NKP keyframes) x DIM=2.
// Per segment i (n = idx[i+1]-idx[i]):
//   da = (dy - n*v0 - n(n+1)/2*a0) / (n(n+1)(n+2)/6)
//   pos_k = y0 + k*v0 + k(k+1)/2*a0 + k(k+1)(k+2)/6*da   (k=1..n)
//   v0 += n*a0 + n(n+1)/2*da ;  a0 += n*da
// n<=1: emit y1; a0 = (y1-y0) - v0; v0 = y1-y0.
//
// Mapping: 4 lanes per batch element run the 10-step recurrence
// redundantly (cheap); lane r writes rows k=r+1, r+5, ... into a padded
// LDS tile [64][rows+2] (pad kills the 8-way ds_write_b64 conflict).
// Block-wide float4 copy-out gives fully-coalesced 64B-line stores.
// NSEG templating (host knows nkp) fully unrolls the segment loop so all
// value loads issue up front instead of serializing at ~300cy each.

template <int NSEG>
__global__ __launch_bounds__(256) void interp_kernel(
    const int* __restrict__ index,
    const float2* __restrict__ value,      // B x NKP
    const float2* __restrict__ vinit,      // B x 1
    const float2* __restrict__ ainit,      // B x 1
    float2* __restrict__ out,              // B x rows
    int B, int nkp, int rows, int pad2)    // pad2 = padded row stride (float2)
{
    extern __shared__ float2 lds[];        // [64][pad2]

    int tid = threadIdx.x;
    int gid = blockIdx.x * 256 + tid;
    int b  = gid >> 2;                     // global batch
    int r  = gid & 3;                      // lane-in-group
    int bl = tid >> 2;                     // local batch 0..63

    if (b < B) {
        const float2* __restrict__ vrow = value + (long)b * nkp;
        float2* __restrict__ lrow = lds + bl * pad2;

        float2 v0 = vinit[b];
        float2 a0 = ainit[b];

        constexpr int NKP = NSEG + 1;
        float2 y[NKP];
        int    xi[NKP];
#pragma unroll
        for (int i = 0; i < NKP; ++i) y[i] = vrow[i];   // all loads issue up front
#pragma unroll
        for (int i = 0; i < NKP; ++i) xi[i] = index[i]; // uniform -> s_load

        int off = 0;
#pragma unroll
        for (int i = 0; i < NSEG; ++i) {
            float2 y0 = y[i];
            float2 y1 = y[i + 1];
            int n = xi[i + 1] - xi[i];
            float dyx = y1.x - y0.x;
            float dyy = y1.y - y0.y;

            if (n <= 1) {
                if (r == 0) lrow[off] = y1;
                off += 1;
                a0.x = dyx - v0.x;
                a0.y = dyy - v0.y;
                v0.x = dyx;
                v0.y = dyy;
            } else {
                float fn = (float)n;
                float c1 = fn * (fn + 1.0f) * 0.5f;               // n(n+1)/2
                float c2 = fn * (fn + 1.0f) * (fn + 2.0f) / 6.0f; // n(n+1)(n+2)/6
                float rc2 = __builtin_amdgcn_rcpf(c2);            // ~2^-22 rel err, ok vs threshold
                float dax = (dyx - fn * v0.x - c1 * a0.x) * rc2;
                float day = (dyy - fn * v0.y - c1 * a0.y) * rc2;

                for (int k = r + 1; k <= n; k += 4) {
                    float fk = (float)k;
                    float t2 = fk * (fk + 1.0f) * 0.5f;
                    float t3 = fk * (fk + 1.0f) * (fk + 2.0f) * (1.0f / 6.0f);
                    float2 p;
                    p.x = y0.x + fk * v0.x + t2 * a0.x + t3 * dax;
                    p.y = y0.y + fk * v0.y + t2 * a0.y + t3 * day;
                    lrow[off + k - 1] = p;
                }
                off += n;

                v0.x += fn * a0.x + c1 * dax;
                v0.y += fn * a0.y + c1 * day;
                a0.x += fn * dax;
                a0.y += fn * day;
            }
        }
    }

    __syncthreads();

    // Coalesced copy-out: this block covers batches [blockIdx*64, +nb)
    int first_b = blockIdx.x * 64;
    int nb = B - first_b;
    if (nb > 64) nb = 64;
    if (nb <= 0) return;

    if ((rows & 1) == 0) {
        int rowf4 = rows >> 1;                  // 20
        int padf4 = pad2 >> 1;                  // 21
        const float4* __restrict__ l4 = (const float4*)lds;
        float4* __restrict__ o4 = (float4*)(out + (long)first_b * rows);
        int total4 = nb * rowf4;
        int bb = tid / rowf4;                   // one div, then strength-reduced
        int j  = tid - bb * rowf4;
        int stepb = 256 / rowf4;
        int stepj = 256 - stepb * rowf4;
        for (int f = tid; f < total4; f += 256) {
            o4[f] = l4[bb * padf4 + j];
            j += stepj; bb += stepb;
            if (j >= rowf4) { j -= rowf4; ++bb; }
        }
    } else {                                    // generic fallback (rows odd)
        int total2 = nb * rows;
        float2* __restrict__ o2 = out + (long)first_b * rows;
        for (int f = tid; f < total2; f += 256) {
            int bb = f / rows;
            int j  = f - bb * rows;
            o2[f] = lds[bb * pad2 + j];
        }
    }
}

// Runtime-NSEG fallback for unexpected nkp.
__global__ __launch_bounds__(256) void interp_kernel_gen(
    const int* __restrict__ index,
    const float2* __restrict__ value,
    const float2* __restrict__ vinit,
    const float2* __restrict__ ainit,
    float2* __restrict__ out,
    int B, int nkp, int rows, int pad2)
{
    extern __shared__ float2 lds[];
    int tid = threadIdx.x;
    int gid = blockIdx.x * 256 + tid;
    int b  = gid >> 2;
    int r  = gid & 3;
    int bl = tid >> 2;

    if (b < B) {
        const float2* __restrict__ vrow = value + (long)b * nkp;
        float2* __restrict__ lrow = lds + bl * pad2;
        float2 v0 = vinit[b];
        float2 a0 = ainit[b];
        float2 y0 = vrow[0];
        int x0 = index[0];
        int off = 0;
        for (int i = 0; i < nkp - 1; ++i) {
            float2 y1 = vrow[i + 1];
            int x1 = index[i + 1];
            int n = x1 - x0; x0 = x1;
            float dyx = y1.x - y0.x, dyy = y1.y - y0.y;
            if (n <= 1) {
                if (r == 0) lrow[off] = y1;
                off += 1;
                a0.x = dyx - v0.x; a0.y = dyy - v0.y;
                v0.x = dyx; v0.y = dyy;
            } else {
                float fn = (float)n;
                float c1 = fn * (fn + 1.0f) * 0.5f;
                float c2 = fn * (fn + 1.0f) * (fn + 2.0f) / 6.0f;
                float dax = (dyx - fn * v0.x - c1 * a0.x) / c2;
                float day = (dyy - fn * v0.y - c1 * a0.y) / c2;
                for (int k = r + 1; k <= n; k += 4) {
                    float fk = (float)k;
                    float t2 = fk * (fk + 1.0f) * 0.5f;
                    float t3 = fk * (fk + 1.0f) * (fk + 2.0f) * (1.0f / 6.0f);
                    float2 p;
                    p.x = y0.x + fk * v0.x + t2 * a0.x + t3 * dax;
                    p.y = y0.y + fk * v0.y + t2 * a0.y + t3 * day;
                    lrow[off + k - 1] = p;
                }
                off += n;
                v0.x += fn * a0.x + c1 * dax;
                v0.y += fn * a0.y + c1 * day;
                a0.x += fn * dax;
                a0.y += fn * day;
            }
            y0 = y1;
        }
    }

    __syncthreads();

    int first_b = blockIdx.x * 64;
    int nb = B - first_b;
    if (nb > 64) nb = 64;
    if (nb <= 0) return;
    int total2 = nb * rows;
    float2* __restrict__ o2 = out + (long)first_b * rows;
    for (int f = tid; f < total2; f += 256) {
        int bb = f / rows;
        int j  = f - bb * rows;
        o2[f] = lds[bb * pad2 + j];
    }
}

extern "C" void kernel_launch(void* const* d_in, const int* in_sizes, int n_in,
                              void* d_out, int out_size, void* d_ws, size_t ws_size,
                              hipStream_t stream) {
    const int*    index = (const int*)d_in[0];
    const float2* value = (const float2*)d_in[1];
    const float2* vinit = (const float2*)d_in[2];
    const float2* ainit = (const float2*)d_in[3];
    float2*       out   = (float2*)d_out;

    int nkp  = in_sizes[0];                 // 11
    int B    = in_sizes[1] / (nkp * 2);     // 262144
    int rows = out_size / (B * 2);          // 40

    int pad2 = rows + 2;                    // keeps float4 alignment, breaks bank stride
    size_t smem = (size_t)64 * pad2 * sizeof(float2);   // 21504 B for rows=40

    int total = B * 4;                      // 4 lanes per batch element
    dim3 grid((total + 255) / 256);

    if (nkp == 11) {
        interp_kernel<10><<<grid, 256, smem, stream>>>(index, value, vinit, ainit, out, B, nkp, rows, pad2);
    } else {
        interp_kernel_gen<<<grid, 256, smem, stream>>>(index, value, vinit, ainit, out, B, nkp, rows, pad2);
    }
}

// Round 5
// 23.894 us; speedup vs baseline: 1.6415x; 1.1757x over previous
//
#include <hip/hip_runtime.h>

// LinearAccInterpolation: B x (NKP keyframes) x DIM=2.
// Per segment i (n = idx[i+1]-idx[i]):
//   da = (dy - n*v0 - n(n+1)/2*a0) / (n(n+1)(n+2)/6)
//   pos_k = y0 + k*v0 + k(k+1)/2*a0 + k(k+1)(k+2)/6*da   (k=1..n)
//   v0 += n*a0 + n(n+1)/2*da ;  a0 += n*da
// n<=1: emit y1; a0 = (y1-y0) - v0; v0 = y1-y0.
//
// Structure per 256-thread block (64 batches, 4 lanes/batch):
//   A: dense float4 copy-in of value slab + inits (global->LDS) — replaces
//      4x-redundant 11-per-lane float2 loads that cost ~22 cache lines per
//      wave instruction in the TA pipe.
//   B1: LDS -> registers (y[], v0, a0), barrier, then LDS is reused
//   B2: recurrence (fully unrolled via NSEG template), rows -> padded LDS tile
//   C: fully-coalesced NONTEMPORAL float4 copy-out (write-once 84MB stream,
//      bypass L2 so it doesn't thrash the read stream). Uses a clang
//      ext_vector_type alias since __builtin_nontemporal_store rejects
//      HIP_vector_type<float,4>.

typedef float f4 __attribute__((ext_vector_type(4)));

template <int NSEG>
__global__ __launch_bounds__(256) void interp_kernel(
    const int* __restrict__ index,
    const float2* __restrict__ value,      // B x NKP
    const float2* __restrict__ vinit,      // B x 1
    const float2* __restrict__ ainit,      // B x 1
    float2* __restrict__ out,              // B x rows
    int B, int rows, int pad2)             // pad2 = padded row stride (float2)
{
    constexpr int NKP = NSEG + 1;
    extern __shared__ char smem[];
    // Phase A/B1 layout:
    float2* inv = (float2*)smem;                       // [64*NKP] value slab
    float2* ivi = (float2*)(smem + 64 * NKP * 8);      // [64] init_speed
    float2* iai = (float2*)(smem + 64 * NKP * 8 + 512);// [64] init_acc
    // Phase B2/C layout (aliased, reused after B1):
    float2* outt = (float2*)smem;                      // [64][pad2]

    int tid = threadIdx.x;
    int first_b = blockIdx.x * 64;
    int nb = B - first_b;
    if (nb > 64) nb = 64;
    bool full = (nb == 64);

    // ---- Phase A: copy-in ----
    if (full) {
        const f4* gv4 = (const f4*)(value + (long)first_b * NKP);
        f4* l4 = (f4*)inv;
        constexpr int NV4 = 64 * NKP / 2;              // 352 for NKP=11
        for (int f = tid; f < NV4; f += 256) l4[f] = gv4[f];
        if (tid < 32) {
            ((f4*)ivi)[tid] = ((const f4*)(vinit + first_b))[tid];
        } else if (tid < 64) {
            ((f4*)iai)[tid - 32] = ((const f4*)(ainit + first_b))[tid - 32];
        }
    } else {
        for (int f = tid; f < nb * NKP; f += 256) inv[f] = value[(long)first_b * NKP + f];
        if (tid < nb) ivi[tid] = vinit[first_b + tid];
        else if (tid < 2 * nb) iai[tid - nb] = ainit[first_b + tid - nb];
    }
    __syncthreads();

    // ---- Phase B1: LDS -> registers ----
    int bl = tid >> 2;                     // local batch 0..63
    int r  = tid & 3;                      // lane-in-group
    bool active = (bl < nb);

    float2 y[NKP];
    float2 v0, a0;
    int xi[NKP];
#pragma unroll
    for (int i = 0; i < NKP; ++i) xi[i] = index[i];    // uniform -> s_load
    if (active) {
#pragma unroll
        for (int i = 0; i < NKP; ++i) y[i] = inv[bl * NKP + i];
        v0 = ivi[bl];
        a0 = iai[bl];
    } else {
        v0 = a0 = make_float2(0.f, 0.f);
#pragma unroll
        for (int i = 0; i < NKP; ++i) y[i] = make_float2(0.f, 0.f);
    }
    __syncthreads();   // everyone done reading; LDS now reusable as out tile

    // ---- Phase B2: recurrence -> padded LDS tile ----
    if (active) {
        float2* __restrict__ lrow = outt + bl * pad2;
        int off = 0;
#pragma unroll
        for (int i = 0; i < NSEG; ++i) {
            float2 y0 = y[i];
            float2 y1 = y[i + 1];
            int n = xi[i + 1] - xi[i];
            float dyx = y1.x - y0.x;
            float dyy = y1.y - y0.y;

            if (n <= 1) {
                if (r == 0) lrow[off] = y1;
                off += 1;
                a0.x = dyx - v0.x;
                a0.y = dyy - v0.y;
                v0.x = dyx;
                v0.y = dyy;
            } else {
                float fn = (float)n;
                float c1 = fn * (fn + 1.0f) * 0.5f;               // n(n+1)/2
                float c2 = fn * (fn + 1.0f) * (fn + 2.0f) / 6.0f; // n(n+1)(n+2)/6
                float rc2 = __builtin_amdgcn_rcpf(c2);            // ~2^-22 rel err
                float dax = (dyx - fn * v0.x - c1 * a0.x) * rc2;
                float day = (dyy - fn * v0.y - c1 * a0.y) * rc2;

                for (int k = r + 1; k <= n; k += 4) {
                    float fk = (float)k;
                    float t2 = fk * (fk + 1.0f) * 0.5f;
                    float t3 = fk * (fk + 1.0f) * (fk + 2.0f) * (1.0f / 6.0f);
                    float2 p;
                    p.x = y0.x + fk * v0.x + t2 * a0.x + t3 * dax;
                    p.y = y0.y + fk * v0.y + t2 * a0.y + t3 * day;
                    lrow[off + k - 1] = p;
                }
                off += n;

                v0.x += fn * a0.x + c1 * dax;
                v0.y += fn * a0.y + c1 * day;
                a0.x += fn * dax;
                a0.y += fn * day;
            }
        }
    }
    __syncthreads();

    // ---- Phase C: coalesced nontemporal copy-out ----
    if (full && (rows & 1) == 0) {
        int rowf4 = rows >> 1;                  // 20
        int padf4 = pad2 >> 1;                  // 21
        const f4* __restrict__ l4 = (const f4*)outt;
        f4* __restrict__ o4 = (f4*)(out + (long)first_b * rows);
        int total4 = 64 * rowf4;
        int bb = tid / rowf4;
        int j  = tid - bb * rowf4;
        int stepb = 256 / rowf4;
        int stepj = 256 - stepb * rowf4;
        for (int f = tid; f < total4; f += 256) {
            __builtin_nontemporal_store(l4[bb * padf4 + j], &o4[f]);
            j += stepj; bb += stepb;
            if (j >= rowf4) { j -= rowf4; ++bb; }
        }
    } else if (nb > 0) {                        // generic tail
        int total2 = nb * rows;
        float2* __restrict__ o2 = out + (long)first_b * rows;
        for (int f = tid; f < total2; f += 256) {
            int bb = f / rows;
            int j  = f - bb * rows;
            o2[f] = outt[bb * pad2 + j];
        }
    }
}

// Runtime-NSEG fallback for unexpected nkp.
__global__ __launch_bounds__(256) void interp_kernel_gen(
    const int* __restrict__ index,
    const float2* __restrict__ value,
    const float2* __restrict__ vinit,
    const float2* __restrict__ ainit,
    float2* __restrict__ out,
    int B, int nkp, int rows, int pad2)
{
    extern __shared__ char smem[];
    float2* lds = (float2*)smem;
    int tid = threadIdx.x;
    int gid = blockIdx.x * 256 + tid;
    int b  = gid >> 2;
    int r  = gid & 3;
    int bl = tid >> 2;

    if (b < B) {
        const float2* __restrict__ vrow = value + (long)b * nkp;
        float2* __restrict__ lrow = lds + bl * pad2;
        float2 v0 = vinit[b];
        float2 a0 = ainit[b];
        float2 y0 = vrow[0];
        int x0 = index[0];
        int off = 0;
        for (int i = 0; i < nkp - 1; ++i) {
            float2 y1 = vrow[i + 1];
            int x1 = index[i + 1];
            int n = x1 - x0; x0 = x1;
            float dyx = y1.x - y0.x, dyy = y1.y - y0.y;
            if (n <= 1) {
                if (r == 0) lrow[off] = y1;
                off += 1;
                a0.x = dyx - v0.x; a0.y = dyy - v0.y;
                v0.x = dyx; v0.y = dyy;
            } else {
                float fn = (float)n;
                float c1 = fn * (fn + 1.0f) * 0.5f;
                float c2 = fn * (fn + 1.0f) * (fn + 2.0f) / 6.0f;
                float dax = (dyx - fn * v0.x - c1 * a0.x) / c2;
                float day = (dyy - fn * v0.y - c1 * a0.y) / c2;
                for (int k = r + 1; k <= n; k += 4) {
                    float fk = (float)k;
                    float t2 = fk * (fk + 1.0f) * 0.5f;
                    float t3 = fk * (fk + 1.0f) * (fk + 2.0f) * (1.0f / 6.0f);
                    float2 p;
                    p.x = y0.x + fk * v0.x + t2 * a0.x + t3 * dax;
                    p.y = y0.y + fk * v0.y + t2 * a0.y + t3 * day;
                    lrow[off + k - 1] = p;
                }
                off += n;
                v0.x += fn * a0.x + c1 * dax;
                v0.y += fn * a0.y + c1 * day;
                a0.x += fn * dax;
                a0.y += fn * day;
            }
            y0 = y1;
        }
    }

    __syncthreads();

    int first_b = blockIdx.x * 64;
    int nb = B - first_b;
    if (nb > 64) nb = 64;
    if (nb <= 0) return;
    int total2 = nb * rows;
    float2* __restrict__ o2 = out + (long)first_b * rows;
    for (int f = tid; f < total2; f += 256) {
        int bb = f / rows;
        int j  = f - bb * rows;
        o2[f] = lds[bb * pad2 + j];
    }
}

extern "C" void kernel_launch(void* const* d_in, const int* in_sizes, int n_in,
                              void* d_out, int out_size, void* d_ws, size_t ws_size,
                              hipStream_t stream) {
    const int*    index = (const int*)d_in[0];
    const float2* value = (const float2*)d_in[1];
    const float2* vinit = (const float2*)d_in[2];
    const float2* ainit = (const float2*)d_in[3];
    float2*       out   = (float2*)d_out;

    int nkp  = in_sizes[0];                 // 11
    int B    = in_sizes[1] / (nkp * 2);     // 262144
    int rows = out_size / (B * 2);          // 40

    int pad2 = rows + 2;                    // float4-aligned rows, breaks bank stride
    size_t smem_out = (size_t)64 * pad2 * sizeof(float2);       // 21504 for rows=40
    size_t smem_in  = (size_t)64 * nkp * sizeof(float2) + 1024; // 6656 for nkp=11
    size_t smem = smem_out > smem_in ? smem_out : smem_in;

    dim3 grid((B + 63) / 64);

    if (nkp == 11) {
        interp_kernel<10><<<grid, 256, smem, stream>>>(index, value, vinit, ainit, out, B, rows, pad2);
    } else {
        interp_kernel_gen<<<grid, 256, smem, stream>>>(index, value, vinit, ainit, out, B, nkp, rows, pad2);
    }
}